// Round 9
// baseline (48.997 us; speedup 1.0000x reference)
//
#include <hip/hip_runtime.h>

#define NK 50
#define D  256
#define NW 8          // waves per block (512 threads)
#define RPW 7         // rows per wave: k = wave + 8*i
#define PFR 24        // rows of next sample prefetched into LDS (3 per wave)
#define GRIDSZ 1024   // persistent: exactly 4 blocks/CU x 256 CU

typedef float f4 __attribute__((ext_vector_type(4)));
typedef const __attribute__((address_space(1))) void* as1cv;
typedef __attribute__((address_space(3))) void*       as3v;

__device__ __forceinline__ void glds16(const float* g, float* s) {
    // 64 lanes x 16B -> LDS row base + lane*16 (linear dest; zero VGPR cost)
    __builtin_amdgcn_global_load_lds((as1cv)g, (as3v)s, 16, 0, 0);
}

// raw barriers: lgkm-only keeps the glds prefetch stream in flight across phases
#define BAR_LGKM() asm volatile("s_waitcnt lgkmcnt(0)\n\ts_barrier" ::: "memory")
#define BAR_ALL()  asm volatile("s_waitcnt vmcnt(0) lgkmcnt(0)\n\ts_barrier" ::: "memory")

#define NTLOAD(p) __builtin_nontemporal_load(reinterpret_cast<const f4*>(p))

// dots + wave-reduce -> s_attn (frag[] holds this wave's 7 rows)
#define DOTS()                                                          \
    _Pragma("unroll")                                                   \
    for (int i_ = 0; i_ < RPW; ++i_) {                                  \
        const int k_ = wave + i_ * NW;                                  \
        if (k_ < NK) {                                                  \
            const f4 a_ = frag[i_];                                     \
            float p_ = a_.x*c4.x + a_.y*c4.y + a_.z*c4.z + a_.w*c4.w;   \
            _Pragma("unroll")                                           \
            for (int o_ = 32; o_ >= 1; o_ >>= 1)                        \
                p_ += __shfl_xor(p_, o_, 64);                           \
            if (lane == 0) s_attn[k_] = p_;                             \
        }                                                               \
    }

// prefetch rows 0..PFR-1 of sample SN into s_buf (rows w, w+8, w+16 — uniform)
#define PREFETCH(SN)                                                    \
    {                                                                   \
        const float* ip_ = interest + (size_t)(SN) * (NK * D);          \
        _Pragma("unroll")                                               \
        for (int i_ = 0; i_ < 3; ++i_) {                                \
            const int r_ = wave + i_ * NW;                              \
            glds16(ip_ + (size_t)r_ * D + lane * 4, &s_buf[r_ * D]);    \
        }                                                               \
    }

// rank + weighted sum + store for sample S (call after DOTS + BAR_LGKM)
#define TAIL(S, CNT)                                                    \
    {                                                                   \
        if (wave == 0) {                                                \
            int c_ = (CNT) < 1 ? 1 : (CNT);                             \
            int dk_ = (int)ceilf(log2f(5.0f * (float)c_));              \
            dk_ = dk_ < 1 ? 1 : (dk_ > NK ? NK : dk_);                  \
            if (lane < NK) {                                            \
                const float my_ = s_attn[lane];                         \
                int rk_ = 0;                                            \
                _Pragma("unroll 1")                                     \
                for (int j_ = 0; j_ < NK; ++j_) {                       \
                    const float vj_ = s_attn[j_];                       \
                    rk_ += (vj_ > my_) || (vj_ == my_ && j_ < lane);    \
                }                                                       \
                s_w[lane] = (rk_ < dk_) ? my_ : 0.0f;                   \
            }                                                           \
        }                                                               \
        BAR_LGKM();                                                     \
        {                                                               \
            f4 acc_ = {0.f, 0.f, 0.f, 0.f};                             \
            _Pragma("unroll")                                           \
            for (int i_ = 0; i_ < RPW; ++i_) {                          \
                const int k_ = wave + i_ * NW;                          \
                if (k_ < NK) {                                          \
                    const float w_ = s_w[k_];                           \
                    acc_.x += w_ * frag[i_].x;  acc_.y += w_ * frag[i_].y; \
                    acc_.z += w_ * frag[i_].z;  acc_.w += w_ * frag[i_].w; \
                }                                                       \
            }                                                           \
            *reinterpret_cast<f4*>(&s_part[wave][lane * 4]) = acc_;     \
        }                                                               \
        BAR_LGKM();                                                     \
        if (tid < D) {                                                  \
            float r_ = 0.f;                                             \
            _Pragma("unroll")                                           \
            for (int w_ = 0; w_ < NW; ++w_) r_ += s_part[w_][tid];      \
            out[(size_t)(S) * D + tid] = r_;                            \
        }                                                               \
    }

__global__ __launch_bounds__(512, 8) void ica_kernel(
    const float* __restrict__ interest,   // [bs, 50, 256]
    const float* __restrict__ cand,       // [bs, 256]
    const int*   __restrict__ counts,     // [bs]
    float*       __restrict__ out,        // [bs, 256]
    int bs)
{
    const int tid  = threadIdx.x;
    const int lane = tid & 63;
    const int wave = tid >> 6;
    const int stride = gridDim.x;

    __shared__ float s_attn[NK];
    __shared__ float s_w[NK];
    __shared__ float s_part[NW][D];
    __shared__ float s_buf[PFR * D];      // 24 KB prefetch landing zone

    int s = blockIdx.x;                   // grid <= bs
    f4  frag[RPW];
    f4  c4;
    int cnt;

    // ---- peeled iteration 0: all 7 rows from global ----
    {
        const float* irow = interest + (size_t)s * (NK * D);
        #pragma unroll
        for (int i = 0; i < RPW; ++i) {
            const int k = wave + i * NW;
            if (k < NK) frag[i] = NTLOAD(irow + (size_t)k * D + lane * 4);
        }
        c4  = *reinterpret_cast<const f4*>(cand + (size_t)s * D + lane * 4);
        cnt = counts[s];
    }
    int sn = s + stride;
    if (sn < bs) PREFETCH(sn)             // fire-and-forget under iter-0 compute
    DOTS()
    BAR_LGKM();                           // publish s_attn
    TAIL(s, cnt)

    #pragma unroll 1
    while (sn < bs) {
        BAR_ALL();                        // prefetch + prior stores landed; s_buf valid
        s = sn; sn = s + stride;
        const float* irow = interest + (size_t)s * (NK * D);
        // rows 24..49 fresh from global
        #pragma unroll
        for (int i = 3; i < RPW; ++i) {
            const int k = wave + i * NW;
            if (k < NK) frag[i] = NTLOAD(irow + (size_t)k * D + lane * 4);
        }
        c4  = *reinterpret_cast<const f4*>(cand + (size_t)s * D + lane * 4);
        cnt = counts[s];
        // rows 0..23 from LDS (prefetched last iteration) into registers
        #pragma unroll
        for (int i = 0; i < 3; ++i) {
            const int r = wave + i * NW;
            frag[i] = *reinterpret_cast<const f4*>(&s_buf[r * D + lane * 4]);
        }
        DOTS()
        BAR_LGKM();                       // publish s_attn; all s_buf reads complete
        if (sn < bs) PREFETCH(sn)         // safe: overwrites s_buf only after barrier
        TAIL(s, cnt)
    }
}

extern "C" void kernel_launch(void* const* d_in, const int* in_sizes, int n_in,
                              void* d_out, int out_size, void* d_ws, size_t ws_size,
                              hipStream_t stream) {
    const float* interest = (const float*)d_in[0];   // [bs,50,256]
    const float* cand     = (const float*)d_in[1];   // [bs,256]
    const int*   counts   = (const int*)d_in[2];     // [bs]
    float*       out      = (float*)d_out;           // [bs,256]

    const int bs   = in_sizes[2];                    // 4096
    const int grid = (bs < GRIDSZ) ? bs : GRIDSZ;
    ica_kernel<<<grid, 512, 0, stream>>>(interest, cand, counts, out, bs);
}

// Round 10
// 38.106 us; speedup vs baseline: 1.2858x; 1.2858x over previous
//
#include <hip/hip_runtime.h>

#define NK 50
#define D  256
#define NW 8          // waves per block (512 threads)
#define RPW 7         // ceil(NK/NW) rows per wave, register-resident

__global__ __launch_bounds__(512) void ica_kernel(
    const float* __restrict__ interest,   // [bs, 50, 256]
    const float* __restrict__ cand,       // [bs, 256]
    const int*   __restrict__ counts,     // [bs]
    float*       __restrict__ out,        // [bs, 256]
    int bs)
{
    const int b    = blockIdx.x;
    const int tid  = threadIdx.x;
    const int lane = tid & 63;
    const int wave = tid >> 6;

    __shared__ float s_attn[NK];
    __shared__ float s_w[NK];
    __shared__ float s_part[NW][D];

    const float* irow = interest + (size_t)b * NK * D;

    // hoisted scalar load: latency hides under the row-load stream
    const int cnt_raw = counts[b];

    // candidate fragment for this lane (d = lane*4 .. lane*4+3)
    const float4 c4 = *reinterpret_cast<const float4*>(cand + (size_t)b * D + lane * 4);

    // ---- phase 1a: issue ALL row loads first (ILP), fragments stay in registers ----
    float4 frag[RPW];
    #pragma unroll
    for (int i = 0; i < RPW; ++i) {
        const int k = wave + i * NW;           // wave-uniform guard
        if (k < NK)
            frag[i] = *reinterpret_cast<const float4*>(irow + (size_t)k * D + lane * 4);
    }

    // ---- phase 1b: dot + wave reduce -> s_attn[k] ----
    #pragma unroll
    for (int i = 0; i < RPW; ++i) {
        const int k = wave + i * NW;
        if (k < NK) {
            const float4 a4 = frag[i];
            float p = a4.x * c4.x + a4.y * c4.y + a4.z * c4.z + a4.w * c4.w;
            #pragma unroll
            for (int off = 32; off >= 1; off >>= 1)
                p += __shfl_xor(p, off, 64);
            if (lane == 0) s_attn[k] = p;
        }
    }
    __syncthreads();

    // ---- phase 2: dyn_K + exact top-k (stable argsort tie semantics) -> weights ----
    if (wave == 0) {
        // dyn_K = ceil(log2(5*cnt)) exactly, via integer bit math:
        // for integer x>1, ceil(log2(x)) == 32 - clz(x-1). 5*cnt in [5,95], never pow2.
        int cnt = cnt_raw < 1 ? 1 : cnt_raw;
        int dynK = 32 - __builtin_clz(5u * (unsigned)cnt - 1u);
        if (dynK < 1)  dynK = 1;
        if (dynK > NK) dynK = NK;

        if (lane < NK) {
            const float my = s_attn[lane];
            int rank = 0;
            // FULL unroll: 50 independent LDS broadcast reads + compares (no dep chain)
            #pragma unroll
            for (int j = 0; j < NK; ++j) {
                const float vj = s_attn[j];
                rank += (vj > my) || (vj == my && j < lane);
            }
            s_w[lane] = (rank < dynK) ? my : 0.0f;
        }
    }
    __syncthreads();

    // ---- phase 3: register-resident weighted sum (no global re-read) ----
    float4 acc = {0.f, 0.f, 0.f, 0.f};
    #pragma unroll
    for (int i = 0; i < RPW; ++i) {
        const int k = wave + i * NW;
        if (k < NK) {
            const float w = s_w[k];
            acc.x += w * frag[i].x;
            acc.y += w * frag[i].y;
            acc.z += w * frag[i].z;
            acc.w += w * frag[i].w;
        }
    }
    *reinterpret_cast<float4*>(&s_part[wave][lane * 4]) = acc;   // stride-1, conflict-free
    __syncthreads();

    // ---- phase 4: cross-wave reduce + coalesced store ----
    if (tid < D) {
        float r = 0.f;
        #pragma unroll
        for (int w = 0; w < NW; ++w)
            r += s_part[w][tid];                                  // stride-1, conflict-free
        out[(size_t)b * D + tid] = r;
    }
}

extern "C" void kernel_launch(void* const* d_in, const int* in_sizes, int n_in,
                              void* d_out, int out_size, void* d_ws, size_t ws_size,
                              hipStream_t stream) {
    const float* interest = (const float*)d_in[0];   // [bs,50,256]
    const float* cand     = (const float*)d_in[1];   // [bs,256]
    const int*   counts   = (const int*)d_in[2];     // [bs]
    float*       out      = (float*)d_out;           // [bs,256]

    const int bs = in_sizes[2];                      // 4096
    ica_kernel<<<bs, 512, 0, stream>>>(interest, cand, counts, out, bs);
}